// Round 9
// baseline (196.122 us; speedup 1.0000x reference)
//
// GRUCell2 MI355X — r17: VALU-lean gather (fp16 tree pre-add, int32 saddr
// offsets, split full/tail chunks) + h-load hoist. Structure frozen from r16
// (batch-per-XCD slice, 512-thr blocks CHB=128, ushort LDS indices, prep
// bf16 weights, MFMA GRU, NT streams).
// r16 post-mortem: occupancy theory CONFIRMED (45->68%, 77->61us). Remaining
// co-limiters per counters (VALU 46%, HBM 24%, nothing saturated): (1) ~16
// VALU/16B-load in the gather (8 cvt + 8 add + 64-bit addr + masks) = ~67K
// VALU cycles/CU = the observed 46%; (2) h loads serialized after the
// barrier. Fix: accumulate each 8-edge chunk in packed fp16 (__hadd2 tree,
// r11-proven numerics, depth-3 err ~0.01 << bf16 quantum 0.0625), convert
// chunk-sum once; int32 (p<<5) offsets -> saddr+voffset form; masks only on
// the single tail chunk; hoist h/bias loads above phase 1.
#include <hip/hip_runtime.h>
#include <hip/hip_fp16.h>

#define NB 8
#define NP 65536
#define NC 32768
#define NF 32
#define NE 524288
#define XROW 40    // shorts per LDS row (80B): 16B-aligned b128 reads, 2-way banks max
#define CHB 128    // channels per block: one per 4-lane group, 512 threads
#define CAP 4096   // staged ushort indices per block (mean 2048, +45 sigma)
#define CONV_BLOCKS 8192   // (NB*NP*NF / 8) / 256

typedef __attribute__((ext_vector_type(4))) float floatx4;
typedef __attribute__((ext_vector_type(8))) short short8;
typedef __attribute__((ext_vector_type(4))) short short4v;

struct h4 { __half2 lo, hi; };          // 8B
struct h8 { __half2 a, b, c, d; };      // 16B: one global_load_dwordx4

__device__ __forceinline__ floatx4 h4tof4(h4 v) {
    float2 a = __half22float2(v.lo);
    float2 b = __half22float2(v.hi);
    floatx4 r; r[0] = a.x; r[1] = a.y; r[2] = b.x; r[3] = b.y;
    return r;
}

__device__ __forceinline__ h8 hadd8(h8 x, h8 y) {
    h8 r;
    r.a = __hadd2(x.a, y.a); r.b = __hadd2(x.b, y.b);
    r.c = __hadd2(x.c, y.c); r.d = __hadd2(x.d, y.d);
    return r;
}

__device__ __forceinline__ short f2b(float f) {
    union { float f; unsigned int u; } v;
    v.f = f;
    unsigned int lsb = (v.u >> 16) & 1u;
    v.u += 0x7fffu + lsb;   // round-to-nearest-even
    return (short)(v.u >> 16);
}

__device__ __forceinline__ int lower_bound(const int* __restrict__ a, int v) {
    int lo = 0, hi = NE;
    while (lo < hi) {
        int mid = (lo + hi) >> 1;
        if (a[mid] < v) lo = mid + 1; else hi = mid;
    }
    return lo;
}

__device__ __forceinline__ float sigmoidf_(float v) {
    return 1.f / (1.f + __expf(-v));
}
__device__ __forceinline__ float tanhf_(float v) {
    v = fminf(v, 40.f);
    float t = __expf(2.f * v);
    return (t - 1.f) / (t + 1.f);
}

// ---------------------------------------------------------------------------
// Prepass (one kernel, three parts by blockIdx):
//   [0, CONV_BLOCKS):      pathH[i] = fp16(path[i])   (NT streaming convert)
//   [CONV_BLOCKS, +129):   bounds[c] = lower_bound(edge_channel, c)
//   [CONV_BLOCKS+129]:     wb = bf16(W_ih) ++ bf16(W_hh)  (12KB)
// ---------------------------------------------------------------------------
__global__ __launch_bounds__(256) void prep_kernel(
    const float* __restrict__ path, __half* __restrict__ pathH,
    const int* __restrict__ edge_channel, int* __restrict__ bounds,
    const float* __restrict__ W_ih, const float* __restrict__ W_hh,
    unsigned short* __restrict__ wb)
{
    const int bblocks = (NC + 1 + 255) / 256;    // 129
    if (blockIdx.x < CONV_BLOCKS) {
        const size_t id = ((size_t)blockIdx.x * 256 + threadIdx.x) * 8;
        floatx4 v0 = __builtin_nontemporal_load((const floatx4*)(path + id));
        floatx4 v1 = __builtin_nontemporal_load((const floatx4*)(path + id + 4));
        h8 o;
        o.a = __floats2half2_rn(v0[0], v0[1]);
        o.b = __floats2half2_rn(v0[2], v0[3]);
        o.c = __floats2half2_rn(v1[0], v1[1]);
        o.d = __floats2half2_rn(v1[2], v1[3]);
        union { h8 s; floatx4 f; } cv; cv.s = o;
        __builtin_nontemporal_store(cv.f, (floatx4*)(pathH + id));
    } else if (blockIdx.x < CONV_BLOCKS + bblocks) {
        const int c = (blockIdx.x - CONV_BLOCKS) * 256 + threadIdx.x;
        if (c <= NC) bounds[c] = lower_bound(edge_channel, c);
    } else {
        for (int j = threadIdx.x; j < 96 * NF; j += 256) {
            wb[j]           = (unsigned short)f2b(W_ih[j]);
            wb[96 * NF + j] = (unsigned short)f2b(W_hh[j]);
        }
    }
}

// ---------------------------------------------------------------------------
// Fused gather + GRU, batch-sliced. Block = 1 batch x 128 channels, 8 waves.
// Phase 0: stage bf16 weights (pure copy), bounds, ushort edge indices (LDS).
// Phase 1: 128 groups of 4 lanes; group g owns channel c0+g; lane loads 16B
// per edge via dwordx4 (int32 voffset); full 8-edge chunks accumulate in a
// packed-fp16 tree (28 pk-add) and convert the chunk sum ONCE; single masked
// tail chunk. h/bias loads hoisted above phase 1 to hide their latency.
// Phase 2: verified MFMA GRU; NT h loads / out stores protect the L2 slice.
// ---------------------------------------------------------------------------
__global__ __launch_bounds__(512) void fused_gru_new(
    const __half* __restrict__ pathH,        // [B,P,F] fp16 (d_ws)
    const float*  __restrict__ hbuf,         // [B,C,F] fp32
    const unsigned short* __restrict__ wb,   // [2][96][32] bf16 (d_ws)
    const float*  __restrict__ b_ih,         // [96]
    const float*  __restrict__ b_hh,         // [96]
    const int*    __restrict__ edge_path,    // [E]
    const int*    __restrict__ bounds,       // [NC+1] (d_ws)
    float*        __restrict__ out)          // [B,C,F] fp32
{
    const int t    = threadIdx.x;
    const int w    = t >> 6;      // wave 0..7
    const int lane = t & 63;
    const int batch = blockIdx.x & 7;            // == XCD id under %8 dispatch
    const int c0    = (blockIdx.x >> 3) * CHB;

    __shared__ __align__(16) short xs [CHB * XROW];  // x rows bf16, r = c - c0
    __shared__ __align__(16) short wsx[96 * XROW];   // W_ih bf16
    __shared__ __align__(16) short wsh[96 * XROW];   // W_hh bf16
    __shared__ int lbnd[CHB + 1];
    __shared__ unsigned short eidx[CAP];

    // Stage pre-converted bf16 weights -> LDS (pure short8 copy, 384 threads).
    {
        const int j = t;                     // 96*32/8 = 384 chunks
        if (j < 384) {
            const int r = j >> 2, c = (j & 3) * 8;
            *(short8*)(&wsx[r * XROW + c]) = *(const short8*)(&wb[r * NF + c]);
            *(short8*)(&wsh[r * XROW + c]) = *(const short8*)(&wb[96 * NF + r * NF + c]);
        }
    }
    if (t <= CHB) lbnd[t] = bounds[c0 + t];

    // Stage this block's contiguous edge-index range (coalesced, ushort).
    const int base = bounds[c0];                   // broadcast load
    const int cnt  = bounds[c0 + CHB] - base;
    const int cntc = cnt < CAP ? cnt : CAP;
    for (int j = t; j < cntc; j += 512)
        eidx[j] = (unsigned short)edge_path[base + j];

    // Hoist phase-2 global loads: their HBM latency hides under the gather.
    const int quad = lane >> 4;
    const int n16  = lane & 15;
    const int k0   = quad * 8;
    const int rA   = w * 16 + n16;               // 0..127
    const size_t mrow = (size_t)batch * NC + c0; // block's first row
    const float* hrow = hbuf + (mrow + rA) * NF + k0;
    floatx4 h0 = __builtin_nontemporal_load((const floatx4*)(hrow));
    floatx4 h1 = __builtin_nontemporal_load((const floatx4*)(hrow + 4));
    float bxv[6], bhv[6];
    #pragma unroll
    for (int tt = 0; tt < 6; ++tt) {
        bxv[tt] = b_ih[16 * tt + n16];
        bhv[tt] = b_hh[16 * tt + n16];
    }
    __syncthreads();

    // ---- Phase 1: gather from this batch's 4MB L2-resident slice.
    const int g  = t >> 2;           // 0..127: channel group (4 lanes)
    const int fh = t & 3;            // feature half: features fh*8..fh*8+7
    const __half* pbase = pathH + (size_t)batch * (NP * NF) + fh * 8;

    const int ls = lbnd[g];
    const int le = lbnd[g + 1];
    floatx4 accL = {0.f, 0.f, 0.f, 0.f};
    floatx4 accH = {0.f, 0.f, 0.f, 0.f};
    const __half2 hz = __half2half2(__float2half(0.f));

    auto run_gather = [&](auto IDX) {
        int i = ls;
        // Full chunks: no masking; fp16 tree; one convert per chunk.
        for (; i + 8 <= le; i += 8) {
            int p0 = IDX(i),     p1 = IDX(i + 1), p2 = IDX(i + 2), p3 = IDX(i + 3);
            int p4 = IDX(i + 4), p5 = IDX(i + 5), p6 = IDX(i + 6), p7 = IDX(i + 7);
            h8 v0 = *(const h8*)(pbase + (p0 << 5));
            h8 v1 = *(const h8*)(pbase + (p1 << 5));
            h8 v2 = *(const h8*)(pbase + (p2 << 5));
            h8 v3 = *(const h8*)(pbase + (p3 << 5));
            h8 v4 = *(const h8*)(pbase + (p4 << 5));
            h8 v5 = *(const h8*)(pbase + (p5 << 5));
            h8 v6 = *(const h8*)(pbase + (p6 << 5));
            h8 v7 = *(const h8*)(pbase + (p7 << 5));
            h8 s = hadd8(hadd8(hadd8(v0, v1), hadd8(v2, v3)),
                         hadd8(hadd8(v4, v5), hadd8(v6, v7)));
            h4 slo; slo.lo = s.a; slo.hi = s.b;
            h4 shi; shi.lo = s.c; shi.hi = s.d;
            accL += h4tof4(slo);
            accH += h4tof4(shi);
        }
        // Single masked tail chunk (0..7 edges): clamp idx, select-zero.
        if (i < le) {
            int p0 = IDX(i);
            int p1 = IDX(i + 1 < le ? i + 1 : i);
            int p2 = IDX(i + 2 < le ? i + 2 : i);
            int p3 = IDX(i + 3 < le ? i + 3 : i);
            int p4 = IDX(i + 4 < le ? i + 4 : i);
            int p5 = IDX(i + 5 < le ? i + 5 : i);
            int p6 = IDX(i + 6 < le ? i + 6 : i);
            int p7 = IDX(i + 7 < le ? i + 7 : i);
            h8 v0 = *(const h8*)(pbase + (p0 << 5));
            h8 v1 = *(const h8*)(pbase + (p1 << 5));
            h8 v2 = *(const h8*)(pbase + (p2 << 5));
            h8 v3 = *(const h8*)(pbase + (p3 << 5));
            h8 v4 = *(const h8*)(pbase + (p4 << 5));
            h8 v5 = *(const h8*)(pbase + (p5 << 5));
            h8 v6 = *(const h8*)(pbase + (p6 << 5));
            h8 v7 = *(const h8*)(pbase + (p7 << 5));
            if (i + 1 >= le) { v1.a = hz; v1.b = hz; v1.c = hz; v1.d = hz; }
            if (i + 2 >= le) { v2.a = hz; v2.b = hz; v2.c = hz; v2.d = hz; }
            if (i + 3 >= le) { v3.a = hz; v3.b = hz; v3.c = hz; v3.d = hz; }
            if (i + 4 >= le) { v4.a = hz; v4.b = hz; v4.c = hz; v4.d = hz; }
            if (i + 5 >= le) { v5.a = hz; v5.b = hz; v5.c = hz; v5.d = hz; }
            if (i + 6 >= le) { v6.a = hz; v6.b = hz; v6.c = hz; v6.d = hz; }
            if (i + 7 >= le) { v7.a = hz; v7.b = hz; v7.c = hz; v7.d = hz; }
            h8 s = hadd8(hadd8(hadd8(v0, v1), hadd8(v2, v3)),
                         hadd8(hadd8(v4, v5), hadd8(v6, v7)));
            h4 slo; slo.lo = s.a; slo.hi = s.b;
            h4 shi; shi.lo = s.c; shi.hi = s.d;
            accL += h4tof4(slo);
            accH += h4tof4(shi);
        }
    };

    if (cnt <= CAP) {   // block-uniform; statistically always
        run_gather([&](int j) { return (int)eidx[j - base]; });
    } else {
        run_gather([&](int j) { return edge_path[j]; });
    }

    {
        short8 xb;
        #pragma unroll
        for (int q = 0; q < 4; ++q) { xb[q] = f2b(accL[q]); xb[4 + q] = f2b(accH[q]); }
        *(short8*)(&xs[g * XROW + fh * 8]) = xb;
    }
    __syncthreads();

    // ---- Phase 2: fused GRU via mfma_f32_16x16x32_bf16 (verified).
    short8 ax = *(const short8*)(&xs[rA * XROW + k0]);
    short8 ah;
    #pragma unroll
    for (int q = 0; q < 4; ++q) { ah[q] = f2b(h0[q]); ah[4 + q] = f2b(h1[q]); }

    const floatx4 zero = {0.f, 0.f, 0.f, 0.f};
    // r,z gates: x- and h-MFMAs chain into ONE accumulator. n gate needs
    // xn and hn separate (r gates hn).
    floatx4 gg[4];
    #pragma unroll
    for (int tt = 0; tt < 4; ++tt) {
        short8 bw = *(const short8*)(&wsx[(16 * tt + n16) * XROW + k0]);
        floatx4 a = __builtin_amdgcn_mfma_f32_16x16x32_bf16(ax, bw, zero, 0, 0, 0);
        bw = *(const short8*)(&wsh[(16 * tt + n16) * XROW + k0]);
        gg[tt] = __builtin_amdgcn_mfma_f32_16x16x32_bf16(ah, bw, a, 0, 0, 0);
    }
    floatx4 nx[2], nh[2];
    #pragma unroll
    for (int u = 0; u < 2; ++u) {
        const int tt = 4 + u;
        short8 bw = *(const short8*)(&wsx[(16 * tt + n16) * XROW + k0]);
        nx[u] = __builtin_amdgcn_mfma_f32_16x16x32_bf16(ax, bw, zero, 0, 0, 0);
        bw = *(const short8*)(&wsh[(16 * tt + n16) * XROW + k0]);
        nh[u] = __builtin_amdgcn_mfma_f32_16x16x32_bf16(ah, bw, zero, 0, 0, 0);
    }

    // Epilogue in C-layout (col = lane&15, row = quad*4+i), fp32 h blend.
    // NT loads/stores: keep the 32MB h/out streams out of the L2 slice.
    #pragma unroll
    for (int i = 0; i < 4; ++i) {
        const int r2 = w * 16 + quad * 4 + i;
        const size_t m = mrow + r2;
        float r0 = sigmoidf_(gg[0][i] + bxv[0] + bhv[0]);
        float r1 = sigmoidf_(gg[1][i] + bxv[1] + bhv[1]);
        float z0 = sigmoidf_(gg[2][i] + bxv[2] + bhv[2]);
        float z1 = sigmoidf_(gg[3][i] + bxv[3] + bhv[3]);
        float n0 = tanhf_(nx[0][i] + bxv[4] + r0 * (nh[0][i] + bhv[4]));
        float n1 = tanhf_(nx[1][i] + bxv[5] + r1 * (nh[1][i] + bhv[5]));
        float hv0 = __builtin_nontemporal_load(&hbuf[m * NF + n16]);
        float hv1 = __builtin_nontemporal_load(&hbuf[m * NF + 16 + n16]);
        __builtin_nontemporal_store((1.f - z0) * n0 + z0 * hv0, &out[m * NF + n16]);
        __builtin_nontemporal_store((1.f - z1) * n1 + z1 * hv1, &out[m * NF + 16 + n16]);
    }
}

// ---------------------------------------------------------------------------
// Fallback (ws too small): r11's verified fp32-gather fused kernel,
// 8 channels/block, in-kernel binary search.
// ---------------------------------------------------------------------------
__global__ __launch_bounds__(256) void fused_gru_fb(
    const float*  __restrict__ path,
    const float*  __restrict__ hbuf,
    const float*  __restrict__ W_ih,
    const float*  __restrict__ W_hh,
    const float*  __restrict__ b_ih,
    const float*  __restrict__ b_hh,
    const int*    __restrict__ edge_path,
    const int*    __restrict__ edge_channel,
    float*        __restrict__ out)
{
    const int t    = threadIdx.x;
    const int w    = t >> 6;
    const int lane = t & 63;
    const int cblk = blockIdx.x * 8;

    __shared__ int bounds[9];
    __shared__ __align__(16) short xs [64 * XROW];
    __shared__ __align__(16) short wsx[96 * XROW];
    __shared__ __align__(16) short wsh[96 * XROW];

    if (t < 9) bounds[t] = lower_bound(edge_channel, cblk + t);
    for (int idx = t; idx < 96 * NF; idx += 256) {
        int r = idx >> 5, c = idx & 31;
        wsx[r * XROW + c] = f2b(W_ih[idx]);
        wsh[r * XROW + c] = f2b(W_hh[idx]);
    }
    __syncthreads();

    const int b  = lane >> 3;
    const int fq = lane & 7;
    const float* prow = path + (size_t)b * (NP * NF) + fq * 4;

    #pragma unroll
    for (int half = 0; half < 2; ++half) {
        const int cl = w * 2 + half;
        const int s = __builtin_amdgcn_readfirstlane(bounds[cl]);
        const int e = __builtin_amdgcn_readfirstlane(bounds[cl + 1]);
        floatx4 acc = {0.f, 0.f, 0.f, 0.f};
        int i = s;
        for (; i + 8 <= e; i += 8) {
            int p0 = edge_path[i + 0], p1 = edge_path[i + 1];
            int p2 = edge_path[i + 2], p3 = edge_path[i + 3];
            int p4 = edge_path[i + 4], p5 = edge_path[i + 5];
            int p6 = edge_path[i + 6], p7 = edge_path[i + 7];
            floatx4 g0 = *(const floatx4*)(prow + (size_t)p0 * NF);
            floatx4 g1 = *(const floatx4*)(prow + (size_t)p1 * NF);
            floatx4 g2 = *(const floatx4*)(prow + (size_t)p2 * NF);
            floatx4 g3 = *(const floatx4*)(prow + (size_t)p3 * NF);
            floatx4 g4 = *(const floatx4*)(prow + (size_t)p4 * NF);
            floatx4 g5 = *(const floatx4*)(prow + (size_t)p5 * NF);
            floatx4 g6 = *(const floatx4*)(prow + (size_t)p6 * NF);
            floatx4 g7 = *(const floatx4*)(prow + (size_t)p7 * NF);
            acc += ((g0 + g1) + (g2 + g3)) + ((g4 + g5) + (g6 + g7));
        }
        for (; i < e; ++i)
            acc += *(const floatx4*)(prow + (size_t)edge_path[i] * NF);
        short4v xb;
        #pragma unroll
        for (int q = 0; q < 4; ++q) xb[q] = f2b(acc[q]);
        *(short4v*)(&xs[(b * 8 + cl) * XROW + fq * 4]) = xb;
    }
    __syncthreads();

    const int quad = lane >> 4;
    const int n16  = lane & 15;
    const int k0   = quad * 8;

    const int rA = w * 16 + n16;
    short8 ax = *(const short8*)(&xs[rA * XROW + k0]);
    const int bA = rA >> 3;
    const int cA = cblk + (rA & 7);
    const float* hrow = hbuf + ((size_t)bA * NC + cA) * NF + k0;
    floatx4 h0 = *(const floatx4*)(hrow);
    floatx4 h1 = *(const floatx4*)(hrow + 4);
    short8 ah;
    #pragma unroll
    for (int q = 0; q < 4; ++q) { ah[q] = f2b(h0[q]); ah[4 + q] = f2b(h1[q]); }

    float bxv[6], bhv[6];
    #pragma unroll
    for (int tt = 0; tt < 6; ++tt) {
        bxv[tt] = b_ih[16 * tt + n16];
        bhv[tt] = b_hh[16 * tt + n16];
    }
    const floatx4 zero = {0.f, 0.f, 0.f, 0.f};
    floatx4 g[4];
    #pragma unroll
    for (int tt = 0; tt < 4; ++tt) {
        short8 bw = *(const short8*)(&wsx[(16 * tt + n16) * XROW + k0]);
        floatx4 a = __builtin_amdgcn_mfma_f32_16x16x32_bf16(ax, bw, zero, 0, 0, 0);
        bw = *(const short8*)(&wsh[(16 * tt + n16) * XROW + k0]);
        g[tt] = __builtin_amdgcn_mfma_f32_16x16x32_bf16(ah, bw, a, 0, 0, 0);
    }
    floatx4 nx[2], nh[2];
    #pragma unroll
    for (int u = 0; u < 2; ++u) {
        const int tt = 4 + u;
        short8 bw = *(const short8*)(&wsx[(16 * tt + n16) * XROW + k0]);
        nx[u] = __builtin_amdgcn_mfma_f32_16x16x32_bf16(ax, bw, zero, 0, 0, 0);
        bw = *(const short8*)(&wsh[(16 * tt + n16) * XROW + k0]);
        nh[u] = __builtin_amdgcn_mfma_f32_16x16x32_bf16(ah, bw, zero, 0, 0, 0);
    }
    #pragma unroll
    for (int i = 0; i < 4; ++i) {
        const int r  = w * 16 + quad * 4 + i;
        const int b2 = r >> 3;
        const size_t m = (size_t)b2 * NC + (cblk + (r & 7));
        float r0 = sigmoidf_(g[0][i] + bxv[0] + bhv[0]);
        float r1 = sigmoidf_(g[1][i] + bxv[1] + bhv[1]);
        float z0 = sigmoidf_(g[2][i] + bxv[2] + bhv[2]);
        float z1 = sigmoidf_(g[3][i] + bxv[3] + bhv[3]);
        float n0 = tanhf_(nx[0][i] + bxv[4] + r0 * (nh[0][i] + bhv[4]));
        float n1 = tanhf_(nx[1][i] + bxv[5] + r1 * (nh[1][i] + bhv[5]));
        float hv0 = hbuf[m * NF + n16];
        float hv1 = hbuf[m * NF + 16 + n16];
        out[m * NF + n16]      = (1.f - z0) * n0 + z0 * hv0;
        out[m * NF + 16 + n16] = (1.f - z1) * n1 + z1 * hv1;
    }
}

extern "C" void kernel_launch(void* const* d_in, const int* in_sizes, int n_in,
                              void* d_out, int out_size, void* d_ws, size_t ws_size,
                              hipStream_t stream) {
    const float* path = (const float*)d_in[0];  // [8,65536,32] fp32
    const float* chan = (const float*)d_in[1];  // [8,32768,32] fp32
    const float* W_ih = (const float*)d_in[2];  // [96,32]
    const float* W_hh = (const float*)d_in[3];  // [96,32]
    const float* b_ih = (const float*)d_in[4];  // [96]
    const float* b_hh = (const float*)d_in[5];  // [96]
    const int* edge_path    = (const int*)d_in[6];
    const int* edge_channel = (const int*)d_in[7];
    float* out = (float*)d_out;                 // [8,32768,32] fp32

    const size_t pathH_bytes = (size_t)NB * NP * NF * sizeof(__half);   // 32MB
    const size_t bounds_bytes = (size_t)(NC + 1) * sizeof(int);
    const size_t wb_bytes = (size_t)2 * 96 * NF * sizeof(unsigned short); // 12KB
    const size_t need = pathH_bytes + bounds_bytes + wb_bytes;
    if (ws_size >= need) {
        __half* pathH = (__half*)d_ws;
        int* bounds = (int*)((char*)d_ws + pathH_bytes);
        unsigned short* wb = (unsigned short*)((char*)d_ws + pathH_bytes + bounds_bytes);
        const int bblocks = (NC + 1 + 255) / 256;    // 129
        prep_kernel<<<dim3(CONV_BLOCKS + bblocks + 1), dim3(256), 0, stream>>>(
            path, pathH, edge_channel, bounds, W_ih, W_hh, wb);
        fused_gru_new<<<dim3((NC / CHB) * NB), dim3(512), 0, stream>>>(
            pathH, chan, wb, b_ih, b_hh, edge_path, bounds, out);
    } else {
        fused_gru_fb<<<dim3(NC / 8), dim3(256), 0, stream>>>(
            path, chan, W_ih, W_hh, b_ih, b_hh, edge_path, edge_channel, out);
    }
}